// Round 5
// baseline (4880.588 us; speedup 1.0000x reference)
//
#include <hip/hip_runtime.h>

#define KCW 1024     // num codewords
#define DIM 64       // embedding dim
#define ROWS_BLK 256 // rows per block (2 stripes)
#define STRIPE 128   // rows per stripe
#define CWTILE 128   // codewords per phase (streamed from L1/L2, NOT LDS)

typedef __attribute__((ext_vector_type(4))) float f32x4;

// ---------------------------------------------------------------------------
// Pre-kernel: cnorm[k] = sum_d codebook[k][d]^2   (1024 floats into d_ws)
// ---------------------------------------------------------------------------
__global__ void __launch_bounds__(256) vq_cnorm_kernel(const float* __restrict__ cb,
                                                       float* __restrict__ cnorm) {
    int k = blockIdx.x * blockDim.x + threadIdx.x;
    if (k < KCW) {
        const float4* c4 = (const float4*)(cb + (size_t)k * DIM);
        float s0 = 0.f, s1 = 0.f, s2 = 0.f, s3 = 0.f;
#pragma unroll
        for (int j = 0; j < DIM / 4; j += 4) {
            float4 a = c4[j + 0];
            float4 b = c4[j + 1];
            float4 c = c4[j + 2];
            float4 d = c4[j + 3];
            s0 += a.x * a.x + a.y * a.y + a.z * a.z + a.w * a.w;
            s1 += b.x * b.x + b.y * b.y + b.z * b.z + b.w * b.w;
            s2 += c.x * c.x + c.y * c.y + c.z * c.z + c.w * c.w;
            s3 += d.x * d.x + d.y * d.y + d.z * d.z + d.w * d.w;
        }
        cnorm[k] = (s0 + s1) + (s2 + s3);
    }
}

// sequential x,y,z,w chain — bit-identical association to prior passing rounds
#define DOT4ACC(acc, av, bv)                                               \
    acc = fmaf((av).w, (bv).w,                                             \
          fmaf((av).z, (bv).z,                                             \
          fmaf((av).y, (bv).y,                                             \
          fmaf((av).x, (bv).x, (acc)))));

// one micro-row n against all 8 col fragments of buffer P
#define ROWF(P, n)                                                         \
    DOT4ACC(q##n##a.x, r##P##n, c##P##0) DOT4ACC(q##n##a.y, r##P##n, c##P##1) \
    DOT4ACC(q##n##a.z, r##P##n, c##P##2) DOT4ACC(q##n##a.w, r##P##n, c##P##3) \
    DOT4ACC(q##n##b.x, r##P##n, c##P##4) DOT4ACC(q##n##b.y, r##P##n, c##P##5) \
    DOT4ACC(q##n##b.z, r##P##n, c##P##6) DOT4ACC(q##n##b.w, r##P##n, c##P##7)

#define FMAB(P) ROWF(P, 0) ROWF(P, 1) ROWF(P, 2) ROWF(P, 3)                \
                ROWF(P, 4) ROWF(P, 5) ROWF(P, 6) ROWF(P, 7)

// load one k4-slice: 8 A-rows from LDS (lgkmcnt pipe) + 8 B-cols from
// global/L1 (vmcnt pipe) into buffer P's regs
#define LOADOPS(P, k4v)                                                    \
    {   const int ka_ = (k4v) ^ ty2;                                       \
        r##P##0 = sX[abase + ka_ + 0 * 128];                               \
        r##P##1 = sX[abase + ka_ + 1 * 128];                               \
        r##P##2 = sX[abase + ka_ + 2 * 128];                               \
        r##P##3 = sX[abase + ka_ + 3 * 128];                               \
        r##P##4 = sX[abase + ka_ + 4 * 128];                               \
        r##P##5 = sX[abase + ka_ + 5 * 128];                               \
        r##P##6 = sX[abase + ka_ + 6 * 128];                               \
        r##P##7 = sX[abase + ka_ + 7 * 128];                               \
        c##P##0 = bp[(k4v) + 0 * 128];                                     \
        c##P##1 = bp[(k4v) + 1 * 128];                                     \
        c##P##2 = bp[(k4v) + 2 * 128];                                     \
        c##P##3 = bp[(k4v) + 3 * 128];                                     \
        c##P##4 = bp[(k4v) + 4 * 128];                                     \
        c##P##5 = bp[(k4v) + 5 * 128];                                     \
        c##P##6 = bp[(k4v) + 6 * 128];                                     \
        c##P##7 = bp[(k4v) + 7 * 128]; }

#define UPROW(n, X)                                                        \
    { float s_ = fmaf(-2.f, q##n##X, cn);                                  \
      if (s_ < best##n) { best##n = s_; bidx##n = cwv; } }

#define UPCOL(c, X)                                                        \
    { const float cn = cq[8 * (c)];                                        \
      const int cwv = cwbase + 8 * (c);                                    \
      UPROW(0, X) UPROW(1, X) UPROW(2, X) UPROW(3, X)                      \
      UPROW(4, X) UPROW(5, X) UPROW(6, X) UPROW(7, X) }

#define MERGEPUT(n)                                                        \
    { int rl = 64 * wr + ty + 8 * (n);                                     \
      sMs[rl * 16 + slot] = best##n; sMi[rl * 16 + slot] = bidx##n; }

// ---------------------------------------------------------------------------
// Register-tiled distance GEMM, streaming argmin. B STREAMED FROM L1/L2.
// History: R0/R2 = 390us, VALUBusy 56%, 2 waves/SIMD, load-wait-FMA serial
// at the immovable 128-VGPR budget. R1 (A-in-regs array) and R3 (pinned
// schedule) both spilled to scratch at that same 128 budget — allocator
// will NOT exceed 128 on this toolchain. So: design FOR 128 VGPRs and fix
// the stall with occupancy. Codebook is 256KB (L2-resident; 32KB phase
// tile is L1-resident with 16x intra-block reuse) -> drop sC/sCn staging:
//   * LDS 66560 -> 33280 B -> 4 blocks/CU = 4 waves/SIMD (2x occupancy,
//     matches the 128-VGPR cap; pinned via __launch_bounds__(256,4)).
//   * Phase loop loses BOTH barriers -> waves slip freely; one wave's
//     vmcnt/lgkmcnt sub-batch waits hide under 3 others' FMAs.
//   * A on lgkmcnt (LDS, ~82us wall), B on vmcnt (L1, ~110us wall),
//     VALU ~120us wall — separate pipes, overlapped.
// (R4 run died to a container-level infra failure with no counters; this
// round resubmits the same design — acting on an infra error would be
// acting on noise.)
// Numerics: same values, same FMA chain order, same ascending-cw strict-<
// argmin -> bit-identical to passing kernel.
// ---------------------------------------------------------------------------
__global__ void __launch_bounds__(256, 4)
vq_main_kernel(const float* __restrict__ x,
               const float* __restrict__ cb,
               const float* __restrict__ cnorm,
               float* __restrict__ out_discrete,
               float* __restrict__ out_quant) {
    __shared__ float4 sX[STRIPE * 16];   // 32768 B (merge arrays alias this)
    __shared__ int sFinal[STRIPE];       // 512 B               total 33280

    float* sMs = (float*)sX;                 // 128 rows x 16 slots scores
    int* sMi = ((int*)sX) + STRIPE * 16;     // 128 rows x 16 slots indices

    const int tid = threadIdx.x;
    const int wave = tid >> 6;
    const int lane = tid & 63;
    const int wr = wave >> 1;   // row-group 0..1  (64 rows each)
    const int wc = wave & 1;    // cw-group 0..1   (64 cws each)
    const int ty = lane >> 3;   // 0..7
    const int tx = lane & 7;    // 0..7

    const int row0 = blockIdx.x * ROWS_BLK;
    const float4* xg = (const float4*)x;
    const float4* cbg = (const float4*)cb;
    float4* od4 = (float4*)out_discrete;
    float4* oq4 = (float4*)out_quant;

    const int cnb = 64 * wc + tx;          // first cw of this thread in tile
    const int abase = (64 * wr + ty) * 16; // f4 base of first micro-row
    const int ty2 = ty << 1;
    const int slot = wc * 8 + tx;

    for (int s = 0; s < ROWS_BLK / STRIPE; ++s) {
        const int grow0 = row0 + s * STRIPE;

        __syncthreads();  // (A) prior stripe's sFinal/sMs readers done

        // ---- stage x-stripe: 128 rows x 16 f4, swizzled ----
#pragma unroll
        for (int i = 0; i < 8; ++i) {
            int e = i * 256 + tid;
            int r = e >> 4, ch = e & 15;
            sX[r * 16 + (ch ^ ((r & 7) << 1))] = xg[(size_t)(grow0 + r) * 16 + ch];
        }
        __syncthreads();  // (A2) sX staged

        float best0 = 3.4e38f, best1 = 3.4e38f, best2 = 3.4e38f, best3 = 3.4e38f;
        float best4 = 3.4e38f, best5 = 3.4e38f, best6 = 3.4e38f, best7 = 3.4e38f;
        int bidx0 = 0, bidx1 = 0, bidx2 = 0, bidx3 = 0;
        int bidx4 = 0, bidx5 = 0, bidx6 = 0, bidx7 = 0;

        for (int p = 0; p < KCW / CWTILE; ++p) {
            // B tile base: this thread's first col (p*128 + 64*wc + tx);
            // col stride = 8 rows * 16 f4 = 128 f4
            const float4* bp = cbg + (size_t)(p * CWTILE + cnb) * 16;
            const float* cq = cnorm + p * CWTILE + cnb;

            float4 q0a = {0.f, 0.f, 0.f, 0.f}, q0b = {0.f, 0.f, 0.f, 0.f};
            float4 q1a = {0.f, 0.f, 0.f, 0.f}, q1b = {0.f, 0.f, 0.f, 0.f};
            float4 q2a = {0.f, 0.f, 0.f, 0.f}, q2b = {0.f, 0.f, 0.f, 0.f};
            float4 q3a = {0.f, 0.f, 0.f, 0.f}, q3b = {0.f, 0.f, 0.f, 0.f};
            float4 q4a = {0.f, 0.f, 0.f, 0.f}, q4b = {0.f, 0.f, 0.f, 0.f};
            float4 q5a = {0.f, 0.f, 0.f, 0.f}, q5b = {0.f, 0.f, 0.f, 0.f};
            float4 q6a = {0.f, 0.f, 0.f, 0.f}, q6b = {0.f, 0.f, 0.f, 0.f};
            float4 q7a = {0.f, 0.f, 0.f, 0.f}, q7b = {0.f, 0.f, 0.f, 0.f};

            // ping-pong operand buffers A/B (32 float4)
            float4 rA0, rA1, rA2, rA3, rA4, rA5, rA6, rA7;
            float4 cA0, cA1, cA2, cA3, cA4, cA5, cA6, cA7;
            float4 rB0, rB1, rB2, rB3, rB4, rB5, rB6, rB7;
            float4 cB0, cB1, cB2, cB3, cB4, cB5, cB6, cB7;

            LOADOPS(A, 0)
#pragma unroll
            for (int k4 = 0; k4 < 16; k4 += 2) {
                LOADOPS(B, k4 + 1)   // issue k4+1 loads before k4's FMAs
                FMAB(A)
                if (k4 + 2 < 16) LOADOPS(A, k4 + 2)
                FMAB(B)
            }

            // ---- scores + running argmin (cw ascending -> strict < keeps
            //      earliest index, matching np.argmin) ----
            const int cwbase = p * CWTILE + cnb;
            UPCOL(0, a.x) UPCOL(1, a.y) UPCOL(2, a.z) UPCOL(3, a.w)
            UPCOL(4, b.x) UPCOL(5, b.y) UPCOL(6, b.z) UPCOL(7, b.w)
        }

        __syncthreads();  // (D) compute done -> safe to alias sX with merge

        MERGEPUT(0) MERGEPUT(1) MERGEPUT(2) MERGEPUT(3)
        MERGEPUT(4) MERGEPUT(5) MERGEPUT(6) MERGEPUT(7)
        __syncthreads();  // (E)

        if (tid < STRIPE) {
            float bs = sMs[tid * 16];
            int bi = sMi[tid * 16];
#pragma unroll
            for (int j = 1; j < 16; ++j) {
                float sj = sMs[tid * 16 + j];
                int ij = sMi[tid * 16 + j];
                if (sj < bs || (sj == bs && ij < bi)) { bs = sj; bi = ij; }
            }
            sFinal[tid] = bi;
        }
        __syncthreads();  // (F)

        // ---- epilogue: nontemporal streaming stores (outputs never re-read;
        //      keep the 600 MB write stream out of L2) ----
        {
            size_t obase = (size_t)grow0 * (KCW / 4);
            const int col = tid * 4;
            for (int it = 0; it < STRIPE; ++it) {
                int idx = sFinal[it];  // block-uniform per iteration
                f32x4 v;
                v.x = (col + 0 == idx) ? 1.f : 0.f;
                v.y = (col + 1 == idx) ? 1.f : 0.f;
                v.z = (col + 2 == idx) ? 1.f : 0.f;
                v.w = (col + 3 == idx) ? 1.f : 0.f;
                __builtin_nontemporal_store(v, (f32x4*)&od4[obase + (size_t)it * 256 + tid]);
            }
            size_t qbase = (size_t)grow0 * 16;
#pragma unroll
            for (int it = 0; it < 8; ++it) {
                int cnk = it * 256 + tid;
                int r = cnk >> 4;
                int ch = cnk & 15;
                float4 qv = cbg[(size_t)sFinal[r] * 16 + ch];
                __builtin_nontemporal_store(*(f32x4*)&qv, (f32x4*)&oq4[qbase + cnk]);
            }
        }
    }
}

// ---------------------------------------------------------------------------
extern "C" void kernel_launch(void* const* d_in, const int* in_sizes, int n_in,
                              void* d_out, int out_size, void* d_ws, size_t ws_size,
                              hipStream_t stream) {
    const float* x = (const float*)d_in[0];
    const float* cb = (const float*)d_in[1];
    float* cnorm = (float*)d_ws;  // 1024 floats of scratch

    const int n = in_sizes[0];    // 8388608
    const int rows = n / DIM;     // 131072

    float* out_discrete = (float*)d_out;
    float* out_quant = (float*)d_out + (size_t)rows * KCW;

    vq_cnorm_kernel<<<(KCW + 255) / 256, 256, 0, stream>>>(cb, cnorm);
    vq_main_kernel<<<rows / ROWS_BLK, 256, 0, stream>>>(x, cb, cnorm, out_discrete, out_quant);
}

// Round 6
// 2776.431 us; speedup vs baseline: 1.7579x; 1.7579x over previous
//
#include <hip/hip_runtime.h>

#define KCW 1024     // num codewords
#define DIM 64       // embedding dim
#define ROWS_BLK 256 // rows per block (2 stripes)
#define STRIPE 128   // rows per stripe
#define CWTILE 128   // codewords per phase (streamed from L1/L2, NOT LDS)

typedef __attribute__((ext_vector_type(4))) float f32x4;

// ---------------------------------------------------------------------------
// Pre-kernel: cnorm[k] = sum_d codebook[k][d]^2   (1024 floats into d_ws)
// ---------------------------------------------------------------------------
__global__ void __launch_bounds__(256) vq_cnorm_kernel(const float* __restrict__ cb,
                                                       float* __restrict__ cnorm) {
    int k = blockIdx.x * blockDim.x + threadIdx.x;
    if (k < KCW) {
        const float4* c4 = (const float4*)(cb + (size_t)k * DIM);
        float s0 = 0.f, s1 = 0.f, s2 = 0.f, s3 = 0.f;
#pragma unroll
        for (int j = 0; j < DIM / 4; j += 4) {
            float4 a = c4[j + 0];
            float4 b = c4[j + 1];
            float4 c = c4[j + 2];
            float4 d = c4[j + 3];
            s0 += a.x * a.x + a.y * a.y + a.z * a.z + a.w * a.w;
            s1 += b.x * b.x + b.y * b.y + b.z * b.z + b.w * b.w;
            s2 += c.x * c.x + c.y * c.y + c.z * c.z + c.w * c.w;
            s3 += d.x * d.x + d.y * d.y + d.z * d.z + d.w * d.w;
        }
        cnorm[k] = (s0 + s1) + (s2 + s3);
    }
}

// sequential x,y,z,w chain — bit-identical association to prior passing rounds
#define DOT4ACC(acc, av, bv)                                               \
    acc = fmaf((av).w, (bv).w,                                             \
          fmaf((av).z, (bv).z,                                             \
          fmaf((av).y, (bv).y,                                             \
          fmaf((av).x, (bv).x, (acc)))));

// one micro-row n against all 8 col fragments of buffer P
#define ROWF(P, n)                                                         \
    DOT4ACC(q##n##a.x, r##P##n, c##P##0) DOT4ACC(q##n##a.y, r##P##n, c##P##1) \
    DOT4ACC(q##n##a.z, r##P##n, c##P##2) DOT4ACC(q##n##a.w, r##P##n, c##P##3) \
    DOT4ACC(q##n##b.x, r##P##n, c##P##4) DOT4ACC(q##n##b.y, r##P##n, c##P##5) \
    DOT4ACC(q##n##b.z, r##P##n, c##P##6) DOT4ACC(q##n##b.w, r##P##n, c##P##7)

#define FMAB(P) ROWF(P, 0) ROWF(P, 1) ROWF(P, 2) ROWF(P, 3)                \
                ROWF(P, 4) ROWF(P, 5) ROWF(P, 6) ROWF(P, 7)

// load one k4-slice: 8 A-rows from LDS (lgkmcnt pipe) + 8 B-cols from
// global/L1 (vmcnt pipe) into buffer P's regs
#define LOADOPS(P, k4v)                                                    \
    {   const int ka_ = (k4v) ^ ty2;                                       \
        r##P##0 = sX[abase + ka_ + 0 * 128];                               \
        r##P##1 = sX[abase + ka_ + 1 * 128];                               \
        r##P##2 = sX[abase + ka_ + 2 * 128];                               \
        r##P##3 = sX[abase + ka_ + 3 * 128];                               \
        r##P##4 = sX[abase + ka_ + 4 * 128];                               \
        r##P##5 = sX[abase + ka_ + 5 * 128];                               \
        r##P##6 = sX[abase + ka_ + 6 * 128];                               \
        r##P##7 = sX[abase + ka_ + 7 * 128];                               \
        c##P##0 = bp[(k4v) + 0 * 128];                                     \
        c##P##1 = bp[(k4v) + 1 * 128];                                     \
        c##P##2 = bp[(k4v) + 2 * 128];                                     \
        c##P##3 = bp[(k4v) + 3 * 128];                                     \
        c##P##4 = bp[(k4v) + 4 * 128];                                     \
        c##P##5 = bp[(k4v) + 5 * 128];                                     \
        c##P##6 = bp[(k4v) + 6 * 128];                                     \
        c##P##7 = bp[(k4v) + 7 * 128]; }

#define UPROW(n, X)                                                        \
    { float s_ = fmaf(-2.f, q##n##X, cn);                                  \
      if (s_ < best##n) { best##n = s_; bidx##n = cwv; } }

#define UPCOL(c, X)                                                        \
    { const float cn = cq[8 * (c)];                                        \
      const int cwv = cwbase + 8 * (c);                                    \
      UPROW(0, X) UPROW(1, X) UPROW(2, X) UPROW(3, X)                      \
      UPROW(4, X) UPROW(5, X) UPROW(6, X) UPROW(7, X) }

#define MERGEPUT(n)                                                        \
    { int rl = 64 * wr + ty + 8 * (n);                                     \
      sMs[rl * 16 + slot] = best##n; sMi[rl * 16 + slot] = bidx##n; }

// ---------------------------------------------------------------------------
// Register-tiled distance GEMM, streaming argmin. B STREAMED FROM L1/L2.
// Allocator history on this toolchain:
//   plain (256)            -> 128 VGPR, no spill   (R0/R2, 390us)
//   waves_per_eu(2,2)      -> 128 VGPR             (R2, no change)
//   sched_barrier pinning  -> 128 VGPR + SPILL     (R3, 786us)
//   (256, 4) hint          -> 64 VGPR + SPILL      (R5, 4457us disaster)
// Lesson: occupancy hints only TIGHTEN the budget. Use plain (256); the
// occupancy math closes by itself: LDS 33280 B -> 4 blocks/CU, VGPR 128
// -> 4 waves/SIMD -> 4 blocks/CU. Both limits agree at 2x R0 occupancy.
// Design rationale (R3 pivot): R0's LDS pipe (16 ds_read_b128/k4/wave)
// sat at exact parity with VALU -> barrier-locked 2-wave schedule capped
// at 56% VALUBusy. Streaming B from L1/L2 (codebook 256KB, phase tile
// 32KB, 16x intra-block reuse) halves LDS demand, moves B to the vmcnt
// pipe, deletes both phase barriers, and doubles the wave pool hiding
// the 128-VGPR sub-batch load waits.
// Numerics: same values, same FMA chain order, same ascending-cw strict-<
// argmin -> bit-identical to passing kernel.
// ---------------------------------------------------------------------------
__global__ void __launch_bounds__(256)
vq_main_kernel(const float* __restrict__ x,
               const float* __restrict__ cb,
               const float* __restrict__ cnorm,
               float* __restrict__ out_discrete,
               float* __restrict__ out_quant) {
    __shared__ float4 sX[STRIPE * 16];   // 32768 B (merge arrays alias this)
    __shared__ int sFinal[STRIPE];       // 512 B               total 33280

    float* sMs = (float*)sX;                 // 128 rows x 16 slots scores
    int* sMi = ((int*)sX) + STRIPE * 16;     // 128 rows x 16 slots indices

    const int tid = threadIdx.x;
    const int wave = tid >> 6;
    const int lane = tid & 63;
    const int wr = wave >> 1;   // row-group 0..1  (64 rows each)
    const int wc = wave & 1;    // cw-group 0..1   (64 cws each)
    const int ty = lane >> 3;   // 0..7
    const int tx = lane & 7;    // 0..7

    const int row0 = blockIdx.x * ROWS_BLK;
    const float4* xg = (const float4*)x;
    const float4* cbg = (const float4*)cb;
    float4* od4 = (float4*)out_discrete;
    float4* oq4 = (float4*)out_quant;

    const int cnb = 64 * wc + tx;          // first cw of this thread in tile
    const int abase = (64 * wr + ty) * 16; // f4 base of first micro-row
    const int ty2 = ty << 1;
    const int slot = wc * 8 + tx;

    for (int s = 0; s < ROWS_BLK / STRIPE; ++s) {
        const int grow0 = row0 + s * STRIPE;

        __syncthreads();  // (A) prior stripe's sFinal/sMs readers done

        // ---- stage x-stripe: 128 rows x 16 f4, swizzled ----
#pragma unroll
        for (int i = 0; i < 8; ++i) {
            int e = i * 256 + tid;
            int r = e >> 4, ch = e & 15;
            sX[r * 16 + (ch ^ ((r & 7) << 1))] = xg[(size_t)(grow0 + r) * 16 + ch];
        }
        __syncthreads();  // (A2) sX staged

        float best0 = 3.4e38f, best1 = 3.4e38f, best2 = 3.4e38f, best3 = 3.4e38f;
        float best4 = 3.4e38f, best5 = 3.4e38f, best6 = 3.4e38f, best7 = 3.4e38f;
        int bidx0 = 0, bidx1 = 0, bidx2 = 0, bidx3 = 0;
        int bidx4 = 0, bidx5 = 0, bidx6 = 0, bidx7 = 0;

        for (int p = 0; p < KCW / CWTILE; ++p) {
            // B tile base: this thread's first col (p*128 + 64*wc + tx);
            // col stride = 8 rows * 16 f4 = 128 f4
            const float4* bp = cbg + (size_t)(p * CWTILE + cnb) * 16;
            const float* cq = cnorm + p * CWTILE + cnb;

            float4 q0a = {0.f, 0.f, 0.f, 0.f}, q0b = {0.f, 0.f, 0.f, 0.f};
            float4 q1a = {0.f, 0.f, 0.f, 0.f}, q1b = {0.f, 0.f, 0.f, 0.f};
            float4 q2a = {0.f, 0.f, 0.f, 0.f}, q2b = {0.f, 0.f, 0.f, 0.f};
            float4 q3a = {0.f, 0.f, 0.f, 0.f}, q3b = {0.f, 0.f, 0.f, 0.f};
            float4 q4a = {0.f, 0.f, 0.f, 0.f}, q4b = {0.f, 0.f, 0.f, 0.f};
            float4 q5a = {0.f, 0.f, 0.f, 0.f}, q5b = {0.f, 0.f, 0.f, 0.f};
            float4 q6a = {0.f, 0.f, 0.f, 0.f}, q6b = {0.f, 0.f, 0.f, 0.f};
            float4 q7a = {0.f, 0.f, 0.f, 0.f}, q7b = {0.f, 0.f, 0.f, 0.f};

            // ping-pong operand buffers A/B (32 float4)
            float4 rA0, rA1, rA2, rA3, rA4, rA5, rA6, rA7;
            float4 cA0, cA1, cA2, cA3, cA4, cA5, cA6, cA7;
            float4 rB0, rB1, rB2, rB3, rB4, rB5, rB6, rB7;
            float4 cB0, cB1, cB2, cB3, cB4, cB5, cB6, cB7;

            LOADOPS(A, 0)
#pragma unroll
            for (int k4 = 0; k4 < 16; k4 += 2) {
                LOADOPS(B, k4 + 1)   // issue k4+1 loads before k4's FMAs
                FMAB(A)
                if (k4 + 2 < 16) LOADOPS(A, k4 + 2)
                FMAB(B)
            }

            // ---- scores + running argmin (cw ascending -> strict < keeps
            //      earliest index, matching np.argmin) ----
            const int cwbase = p * CWTILE + cnb;
            UPCOL(0, a.x) UPCOL(1, a.y) UPCOL(2, a.z) UPCOL(3, a.w)
            UPCOL(4, b.x) UPCOL(5, b.y) UPCOL(6, b.z) UPCOL(7, b.w)
        }

        __syncthreads();  // (D) compute done -> safe to alias sX with merge

        MERGEPUT(0) MERGEPUT(1) MERGEPUT(2) MERGEPUT(3)
        MERGEPUT(4) MERGEPUT(5) MERGEPUT(6) MERGEPUT(7)
        __syncthreads();  // (E)

        if (tid < STRIPE) {
            float bs = sMs[tid * 16];
            int bi = sMi[tid * 16];
#pragma unroll
            for (int j = 1; j < 16; ++j) {
                float sj = sMs[tid * 16 + j];
                int ij = sMi[tid * 16 + j];
                if (sj < bs || (sj == bs && ij < bi)) { bs = sj; bi = ij; }
            }
            sFinal[tid] = bi;
        }
        __syncthreads();  // (F)

        // ---- epilogue: nontemporal streaming stores (outputs never re-read;
        //      keep the 600 MB write stream out of L2) ----
        {
            size_t obase = (size_t)grow0 * (KCW / 4);
            const int col = tid * 4;
            for (int it = 0; it < STRIPE; ++it) {
                int idx = sFinal[it];  // block-uniform per iteration
                f32x4 v;
                v.x = (col + 0 == idx) ? 1.f : 0.f;
                v.y = (col + 1 == idx) ? 1.f : 0.f;
                v.z = (col + 2 == idx) ? 1.f : 0.f;
                v.w = (col + 3 == idx) ? 1.f : 0.f;
                __builtin_nontemporal_store(v, (f32x4*)&od4[obase + (size_t)it * 256 + tid]);
            }
            size_t qbase = (size_t)grow0 * 16;
#pragma unroll
            for (int it = 0; it < 8; ++it) {
                int cnk = it * 256 + tid;
                int r = cnk >> 4;
                int ch = cnk & 15;
                float4 qv = cbg[(size_t)sFinal[r] * 16 + ch];
                __builtin_nontemporal_store(*(f32x4*)&qv, (f32x4*)&oq4[qbase + cnk]);
            }
        }
    }
}

// ---------------------------------------------------------------------------
extern "C" void kernel_launch(void* const* d_in, const int* in_sizes, int n_in,
                              void* d_out, int out_size, void* d_ws, size_t ws_size,
                              hipStream_t stream) {
    const float* x = (const float*)d_in[0];
    const float* cb = (const float*)d_in[1];
    float* cnorm = (float*)d_ws;  // 1024 floats of scratch

    const int n = in_sizes[0];    // 8388608
    const int rows = n / DIM;     // 131072

    float* out_discrete = (float*)d_out;
    float* out_quant = (float*)d_out + (size_t)rows * KCW;

    vq_cnorm_kernel<<<(KCW + 255) / 256, 256, 0, stream>>>(cb, cnorm);
    vq_main_kernel<<<rows / ROWS_BLK, 256, 0, stream>>>(x, cb, cnorm, out_discrete, out_quant);
}

// Round 7
// 1003.522 us; speedup vs baseline: 4.8635x; 2.7667x over previous
//
#include <hip/hip_runtime.h>

#define KCW 1024     // num codewords
#define DIM 64       // embedding dim
#define ROWS_BLK 256 // rows per block (2 stripes)
#define STRIPE 128   // rows per stripe
#define CWTILE 128   // codewords per phase (streamed from L1/L2, NOT LDS)

typedef __attribute__((ext_vector_type(4))) float f32x4;

// ---------------------------------------------------------------------------
// Pre-kernel: cnorm[k] = sum_d codebook[k][d]^2   (1024 floats into d_ws)
// ---------------------------------------------------------------------------
__global__ void __launch_bounds__(256) vq_cnorm_kernel(const float* __restrict__ cb,
                                                       float* __restrict__ cnorm) {
    int k = blockIdx.x * blockDim.x + threadIdx.x;
    if (k < KCW) {
        const float4* c4 = (const float4*)(cb + (size_t)k * DIM);
        float s0 = 0.f, s1 = 0.f, s2 = 0.f, s3 = 0.f;
#pragma unroll
        for (int j = 0; j < DIM / 4; j += 4) {
            float4 a = c4[j + 0];
            float4 b = c4[j + 1];
            float4 c = c4[j + 2];
            float4 d = c4[j + 3];
            s0 += a.x * a.x + a.y * a.y + a.z * a.z + a.w * a.w;
            s1 += b.x * b.x + b.y * b.y + b.z * b.z + b.w * b.w;
            s2 += c.x * c.x + c.y * c.y + c.z * c.z + c.w * c.w;
            s3 += d.x * d.x + d.y * d.y + d.z * d.z + d.w * d.w;
        }
        cnorm[k] = (s0 + s1) + (s2 + s3);
    }
}

// sequential x,y,z,w chain — bit-identical association to prior passing rounds
#define DOT4ACC(acc, av, bv)                                               \
    acc = fmaf((av).w, (bv).w,                                             \
          fmaf((av).z, (bv).z,                                             \
          fmaf((av).y, (bv).y,                                             \
          fmaf((av).x, (bv).x, (acc)))));

// one micro-row n against all 8 col fragments (single operand buffer)
#define ROWS1(n)                                                           \
    DOT4ACC(q##n##a.x, r##n, c0) DOT4ACC(q##n##a.y, r##n, c1)              \
    DOT4ACC(q##n##a.z, r##n, c2) DOT4ACC(q##n##a.w, r##n, c3)              \
    DOT4ACC(q##n##b.x, r##n, c4) DOT4ACC(q##n##b.y, r##n, c5)              \
    DOT4ACC(q##n##b.z, r##n, c6) DOT4ACC(q##n##b.w, r##n, c7)

#define UPROW(n, X)                                                        \
    { float s_ = fmaf(-2.f, q##n##X, cn);                                  \
      if (s_ < best##n) { best##n = s_; bidx##n = cwv; } }

#define UPCOL(c, X)                                                        \
    { const float cn = cq[8 * (c)];                                        \
      const int cwv = cwbase + 8 * (c);                                    \
      UPROW(0, X) UPROW(1, X) UPROW(2, X) UPROW(3, X)                      \
      UPROW(4, X) UPROW(5, X) UPROW(6, X) UPROW(7, X) }

#define MERGEPUT(n)                                                        \
    { int rl = 64 * wr + ty + 8 * (n);                                     \
      sMs[rl * 16 + slot] = best##n; sMi[rl * 16 + slot] = bidx##n; }

// ---------------------------------------------------------------------------
// Register-tiled distance GEMM, streaming argmin. B streamed from L1/L2,
// SINGLE operand buffer, k4 loop NOT unrolled.
// Allocator history on this toolchain (the whole story):
//   R0/R2 (sC in LDS, unrolled ping-pong, plain bounds) -> 128 VGPR,
//       remat-serialized loads, VALUBusy 56%, 390us. LDS wall 164us.
//   R1 (areg array)           -> scratch, 2126us
//   R3 (sched_barrier pin)    -> 128 VGPR + spill, 786us
//   R5 ((256,4) hint)         -> 64 VGPR + spill, 4457us
//   R6 (global-B, unrolled ping-pong) -> 256 VGPR + spill, 2357us:
//       the unrolled region let the scheduler hoist long-latency global
//       loads until the live-set burst past 256.
// Lesson: LARGE SCHEDULING REGIONS are the disease. This round keeps the
// 4-block/CU no-sC design but shrinks the region to one k4 iteration
// (#pragma unroll 1) with a single operand set (16 f4 = 64 regs + 64 acc
// ~ 130 VGPR): nothing to hoist, nothing to spill. Per-wave duty ~63%
// (16 loads ~250cy wait + 512cy FMA); 4 waves/SIMD -> TLP saturates the
// VALU where R0's barrier-locked 2 waves could not.
// Walls: VALU ~135us (GEMM+argmin), LDS ~82us, HBM ~120us overlapped.
// Numerics: same values, same FMA chain order, same ascending-cw strict-<
// argmin -> bit-identical to passing kernel.
// ---------------------------------------------------------------------------
__global__ void __launch_bounds__(256)
vq_main_kernel(const float* __restrict__ x,
               const float* __restrict__ cb,
               const float* __restrict__ cnorm,
               float* __restrict__ out_discrete,
               float* __restrict__ out_quant) {
    __shared__ float4 sX[STRIPE * 16];   // 32768 B (merge arrays alias this)
    __shared__ int sFinal[STRIPE];       // 512 B               total 33280

    float* sMs = (float*)sX;                 // 128 rows x 16 slots scores
    int* sMi = ((int*)sX) + STRIPE * 16;     // 128 rows x 16 slots indices

    const int tid = threadIdx.x;
    const int wave = tid >> 6;
    const int lane = tid & 63;
    const int wr = wave >> 1;   // row-group 0..1  (64 rows each)
    const int wc = wave & 1;    // cw-group 0..1   (64 cws each)
    const int ty = lane >> 3;   // 0..7
    const int tx = lane & 7;    // 0..7

    const int row0 = blockIdx.x * ROWS_BLK;
    const float4* xg = (const float4*)x;
    const float4* cbg = (const float4*)cb;
    float4* od4 = (float4*)out_discrete;
    float4* oq4 = (float4*)out_quant;

    const int cnb = 64 * wc + tx;          // first cw of this thread in tile
    const int abase = (64 * wr + ty) * 16; // f4 base of first micro-row
    const int ty2 = ty << 1;
    const int slot = wc * 8 + tx;

    for (int s = 0; s < ROWS_BLK / STRIPE; ++s) {
        const int grow0 = row0 + s * STRIPE;

        __syncthreads();  // (A) prior stripe's sFinal/sMs readers done

        // ---- stage x-stripe: 128 rows x 16 f4, swizzled ----
#pragma unroll
        for (int i = 0; i < 8; ++i) {
            int e = i * 256 + tid;
            int r = e >> 4, ch = e & 15;
            sX[r * 16 + (ch ^ ((r & 7) << 1))] = xg[(size_t)(grow0 + r) * 16 + ch];
        }
        __syncthreads();  // (A2) sX staged

        float best0 = 3.4e38f, best1 = 3.4e38f, best2 = 3.4e38f, best3 = 3.4e38f;
        float best4 = 3.4e38f, best5 = 3.4e38f, best6 = 3.4e38f, best7 = 3.4e38f;
        int bidx0 = 0, bidx1 = 0, bidx2 = 0, bidx3 = 0;
        int bidx4 = 0, bidx5 = 0, bidx6 = 0, bidx7 = 0;

        for (int p = 0; p < KCW / CWTILE; ++p) {
            // B tile base: this thread's first col (p*128 + 64*wc + tx);
            // col stride = 8 rows * 16 f4 = 128 f4
            const float4* bp = cbg + (size_t)(p * CWTILE + cnb) * 16;
            const float* cq = cnorm + p * CWTILE + cnb;

            float4 q0a = {0.f, 0.f, 0.f, 0.f}, q0b = {0.f, 0.f, 0.f, 0.f};
            float4 q1a = {0.f, 0.f, 0.f, 0.f}, q1b = {0.f, 0.f, 0.f, 0.f};
            float4 q2a = {0.f, 0.f, 0.f, 0.f}, q2b = {0.f, 0.f, 0.f, 0.f};
            float4 q3a = {0.f, 0.f, 0.f, 0.f}, q3b = {0.f, 0.f, 0.f, 0.f};
            float4 q4a = {0.f, 0.f, 0.f, 0.f}, q4b = {0.f, 0.f, 0.f, 0.f};
            float4 q5a = {0.f, 0.f, 0.f, 0.f}, q5b = {0.f, 0.f, 0.f, 0.f};
            float4 q6a = {0.f, 0.f, 0.f, 0.f}, q6b = {0.f, 0.f, 0.f, 0.f};
            float4 q7a = {0.f, 0.f, 0.f, 0.f}, q7b = {0.f, 0.f, 0.f, 0.f};

            // one k4 slice per iteration: small scheduling region, ~130 VGPR
#pragma unroll 1
            for (int k4 = 0; k4 < 16; ++k4) {
                const int ka_ = k4 ^ ty2;
                const float4 r0 = sX[abase + ka_ + 0 * 128];
                const float4 r1 = sX[abase + ka_ + 1 * 128];
                const float4 r2 = sX[abase + ka_ + 2 * 128];
                const float4 r3 = sX[abase + ka_ + 3 * 128];
                const float4 r4 = sX[abase + ka_ + 4 * 128];
                const float4 r5 = sX[abase + ka_ + 5 * 128];
                const float4 r6 = sX[abase + ka_ + 6 * 128];
                const float4 r7 = sX[abase + ka_ + 7 * 128];
                const float4 c0 = bp[k4 + 0 * 128];
                const float4 c1 = bp[k4 + 1 * 128];
                const float4 c2 = bp[k4 + 2 * 128];
                const float4 c3 = bp[k4 + 3 * 128];
                const float4 c4 = bp[k4 + 4 * 128];
                const float4 c5 = bp[k4 + 5 * 128];
                const float4 c6 = bp[k4 + 6 * 128];
                const float4 c7 = bp[k4 + 7 * 128];
                ROWS1(0) ROWS1(1) ROWS1(2) ROWS1(3)
                ROWS1(4) ROWS1(5) ROWS1(6) ROWS1(7)
            }

            // ---- scores + running argmin (cw ascending -> strict < keeps
            //      earliest index, matching np.argmin) ----
            const int cwbase = p * CWTILE + cnb;
            UPCOL(0, a.x) UPCOL(1, a.y) UPCOL(2, a.z) UPCOL(3, a.w)
            UPCOL(4, b.x) UPCOL(5, b.y) UPCOL(6, b.z) UPCOL(7, b.w)
        }

        __syncthreads();  // (D) compute done -> safe to alias sX with merge

        MERGEPUT(0) MERGEPUT(1) MERGEPUT(2) MERGEPUT(3)
        MERGEPUT(4) MERGEPUT(5) MERGEPUT(6) MERGEPUT(7)
        __syncthreads();  // (E)

        if (tid < STRIPE) {
            float bs = sMs[tid * 16];
            int bi = sMi[tid * 16];
#pragma unroll
            for (int j = 1; j < 16; ++j) {
                float sj = sMs[tid * 16 + j];
                int ij = sMi[tid * 16 + j];
                if (sj < bs || (sj == bs && ij < bi)) { bs = sj; bi = ij; }
            }
            sFinal[tid] = bi;
        }
        __syncthreads();  // (F)

        // ---- epilogue: nontemporal streaming stores (outputs never re-read;
        //      keep the 600 MB write stream out of L2) ----
        {
            size_t obase = (size_t)grow0 * (KCW / 4);
            const int col = tid * 4;
            for (int it = 0; it < STRIPE; ++it) {
                int idx = sFinal[it];  // block-uniform per iteration
                f32x4 v;
                v.x = (col + 0 == idx) ? 1.f : 0.f;
                v.y = (col + 1 == idx) ? 1.f : 0.f;
                v.z = (col + 2 == idx) ? 1.f : 0.f;
                v.w = (col + 3 == idx) ? 1.f : 0.f;
                __builtin_nontemporal_store(v, (f32x4*)&od4[obase + (size_t)it * 256 + tid]);
            }
            size_t qbase = (size_t)grow0 * 16;
#pragma unroll
            for (int it = 0; it < 8; ++it) {
                int cnk = it * 256 + tid;
                int r = cnk >> 4;
                int ch = cnk & 15;
                float4 qv = cbg[(size_t)sFinal[r] * 16 + ch];
                __builtin_nontemporal_store(*(f32x4*)&qv, (f32x4*)&oq4[qbase + cnk]);
            }
        }
    }
}

// ---------------------------------------------------------------------------
extern "C" void kernel_launch(void* const* d_in, const int* in_sizes, int n_in,
                              void* d_out, int out_size, void* d_ws, size_t ws_size,
                              hipStream_t stream) {
    const float* x = (const float*)d_in[0];
    const float* cb = (const float*)d_in[1];
    float* cnorm = (float*)d_ws;  // 1024 floats of scratch

    const int n = in_sizes[0];    // 8388608
    const int rows = n / DIM;     // 131072

    float* out_discrete = (float*)d_out;
    float* out_quant = (float*)d_out + (size_t)rows * KCW;

    vq_cnorm_kernel<<<(KCW + 255) / 256, 256, 0, stream>>>(cb, cnorm);
    vq_main_kernel<<<rows / ROWS_BLK, 256, 0, stream>>>(x, cb, cnorm, out_discrete, out_quant);
}